// Round 1
// baseline (5681.692 us; speedup 1.0000x reference)
//
#include <hip/hip_runtime.h>
#include <cstdint>
#include <cstddef>

#define SEQ 512
#define BATCH 256
#define SD 1024
#define OD 256

// 8 bf16 values packed as shorts (4 VGPRs) -- guide-verified MFMA frag type
typedef short  bf8   __attribute__((ext_vector_type(8)));
typedef float  f32x4 __attribute__((ext_vector_type(4)));

__device__ __forceinline__ unsigned short f2bf(float f) {
    unsigned u = __float_as_uint(f);
    u += 0x7FFFu + ((u >> 16) & 1u);      // round-to-nearest-even
    return (unsigned short)(u >> 16);
}

__device__ __forceinline__ float fast_tanh(float v) {
    float e = __expf(2.0f * v);           // v_exp_f32 path; saturates correctly at +/-inf
    return 1.0f - 2.0f / (e + 1.0f);
}

// Persistent kernel: 256 wgs = 8 groups (one per XCD via blockIdx&7) x 32 wgs.
// Group handles 32 batches; wg owns 32 state-cols of w_r (bf16 frags in regs)
// and 8 out-cols of w_o. Per step: group barrier -> read full t tile (32x1024)
// -> MFMA recurrent GEMM -> h update (regs) -> tanh -> store t tile -> arrive
// -> output GEMM for previous step's err (off critical path) -> wait.
__global__ void __launch_bounds__(256, 1)
rnn_persistent(const float* __restrict__ x,
               const float* __restrict__ h_init,
               const float* __restrict__ w_r,
               const float* __restrict__ b_r,
               const float* __restrict__ w_o,
               const float* __restrict__ b_o,
               float* __restrict__ out,
               unsigned char* __restrict__ ws)
{
    const int wg   = blockIdx.x;
    const int g    = wg & 7;       // group == XCD (perf heuristic only)
    const int wi   = wg >> 3;      // 0..31 within group
    const int tid  = threadIdx.x;
    const int lane = tid & 63;
    const int wid  = tid >> 6;     // wave 0..3
    const int l15  = lane & 15;
    const int lq   = lane >> 4;    // k-quad 0..3

    unsigned* cnt  = (unsigned*)(ws + (size_t)g * 128);
    unsigned* flag = (unsigned*)(ws + 2048 + (size_t)g * 128);
    unsigned short* tbase = (unsigned short*)(ws + 4096);  // 3 x [256][1024] bf16

    const int batch0 = g * 32;     // group's batch rows
    const int s0 = wi * 32;        // wg's state cols
    const int o0 = wi * 8;         // wg's output cols
    const int k0 = wid * 256;      // wave's K slice

    __shared__ float red1[4][4][4][64];  // [wave][subtile r*2+c][reg][lane]
    __shared__ float red2[4][2][4][64];  // [wave][subtile r][reg][lane]

    // ---- preload w_r slice as B fragments in registers (64 VGPRs) ----
    bf8 B1[2][8];
#pragma unroll
    for (int c = 0; c < 2; ++c) {
#pragma unroll
        for (int kk = 0; kk < 8; ++kk) {
            const float* p = w_r + (size_t)(s0 + c * 16 + l15) * SD + (k0 + kk * 32 + lq * 8);
            bf8 f;
#pragma unroll
            for (int j = 0; j < 8; ++j) f[j] = (short)f2bf(p[j]);
            B1[c][kk] = f;
        }
    }
    // ---- w_o slice (8 real rows, padded to 16 with zeros) ----
    bf8 B2[8];
    {
        const bool v = (l15 < 8);
        const float* p = w_o + (size_t)(o0 + (v ? l15 : 0)) * SD + (k0 + lq * 8);
#pragma unroll
        for (int kk = 0; kk < 8; ++kk) {
            bf8 f;
#pragma unroll
            for (int j = 0; j < 8; ++j) f[j] = v ? (short)f2bf(p[kk * 32 + j]) : (short)0;
            B2[kk] = f;
        }
    }

    // ---- per-thread h ownership: 4 consecutive states of one batch row ----
    const int hr = tid >> 3;            // batch-local row 0..31
    const int hc = (tid & 7) * 4;       // state-local col base
    float4 br4  = *(const float4*)(b_r + s0 + hc);
    float4 hreg = *(const float4*)(h_init + (size_t)(batch0 + hr) * SD + s0 + hc);

    const int st1 = (hr >> 4) * 2 + (hc >> 4);
    const int rg1 = hr & 3;
    const int ln1 = ((hr >> 2) & 3) * 16 + (hc & 15);

    const int er  = hr;                 // err element (row, col)
    const int ec  = tid & 7;
    const int r2  = er >> 4;
    const int rg2 = er & 3;
    const int ln2 = ((er >> 2) & 3) * 16 + ec;
    const float bo = b_o[o0 + ec];

    const size_t t_off = (size_t)(batch0 + hr) * SD + s0 + hc;  // this thread's t elems

    auto arrive = [&](unsigned phase) {
        __syncthreads();  // drains vmcnt: all wg stores are in L2
        if (tid == 0) {
            __builtin_amdgcn_fence(__ATOMIC_RELEASE, "agent");  // wbl2: flush to coherence pt
            unsigned old = __hip_atomic_fetch_add(cnt, 1u, __ATOMIC_RELAXED, __HIP_MEMORY_SCOPE_AGENT);
            if (old == phase * 32u + 31u)
                __hip_atomic_store(flag, phase + 1u, __ATOMIC_RELAXED, __HIP_MEMORY_SCOPE_AGENT);
        }
    };
    auto wait = [&](unsigned phase) {
        if (tid == 0) {
            while (__hip_atomic_load(flag, __ATOMIC_RELAXED, __HIP_MEMORY_SCOPE_AGENT) < phase + 1u)
                __builtin_amdgcn_s_sleep(1);
            __builtin_amdgcn_fence(__ATOMIC_ACQUIRE, "agent");  // inv L1/L2
        }
        __syncthreads();
    };

    auto gemm2 = [&](const unsigned short* tb, int tstep) {
        const unsigned short* a0p = tb + (size_t)(batch0 + l15) * SD + k0 + lq * 8;
        const unsigned short* a1p = a0p + (size_t)16 * SD;
        f32x4 c0 = {0.f, 0.f, 0.f, 0.f}, c1 = {0.f, 0.f, 0.f, 0.f};
#pragma unroll
        for (int kk = 0; kk < 8; ++kk) {
            bf8 a0 = *(const bf8*)(a0p + kk * 32);
            bf8 a1 = *(const bf8*)(a1p + kk * 32);
            c0 = __builtin_amdgcn_mfma_f32_16x16x32_bf16(a0, B2[kk], c0, 0, 0, 0);
            c1 = __builtin_amdgcn_mfma_f32_16x16x32_bf16(a1, B2[kk], c1, 0, 0, 0);
        }
#pragma unroll
        for (int q = 0; q < 4; ++q) { red2[wid][0][q][lane] = c0[q]; red2[wid][1][q][lane] = c1[q]; }
        __syncthreads();
        float sum = red2[0][r2][rg2][ln2] + red2[1][r2][rg2][ln2]
                  + red2[2][r2][rg2][ln2] + red2[3][r2][rg2][ln2];
        size_t oidx = (size_t)tstep * (BATCH * OD) + (size_t)(batch0 + er) * OD + o0 + ec;
        out[oidx] = sum + bo - x[oidx];
    };

    // ---- t0 = tanh(h_init) into buffer 0 ----
    {
        ushort4 pk;
        pk.x = f2bf(fast_tanh(hreg.x));
        pk.y = f2bf(fast_tanh(hreg.y));
        pk.z = f2bf(fast_tanh(hreg.z));
        pk.w = f2bf(fast_tanh(hreg.w));
        *(ushort4*)(tbase + t_off) = pk;
    }
    arrive(0);
    wait(0);

    for (int i = 0; i < SEQ; ++i) {
        const unsigned short* tb = tbase + (size_t)(i % 3) * (BATCH * SD);
        unsigned short* tn = tbase + (size_t)((i + 1) % 3) * (BATCH * SD);

        // ---- recurrent GEMM: C[32x32] over wave's K slice, A direct from global ----
        const unsigned short* a0p = tb + (size_t)(batch0 + l15) * SD + k0 + lq * 8;
        const unsigned short* a1p = a0p + (size_t)16 * SD;
        f32x4 acc00 = {0.f,0.f,0.f,0.f}, acc01 = {0.f,0.f,0.f,0.f};
        f32x4 acc10 = {0.f,0.f,0.f,0.f}, acc11 = {0.f,0.f,0.f,0.f};
#pragma unroll
        for (int kk = 0; kk < 8; ++kk) {
            bf8 a0 = *(const bf8*)(a0p + kk * 32);
            bf8 a1 = *(const bf8*)(a1p + kk * 32);
            acc00 = __builtin_amdgcn_mfma_f32_16x16x32_bf16(a0, B1[0][kk], acc00, 0, 0, 0);
            acc01 = __builtin_amdgcn_mfma_f32_16x16x32_bf16(a0, B1[1][kk], acc01, 0, 0, 0);
            acc10 = __builtin_amdgcn_mfma_f32_16x16x32_bf16(a1, B1[0][kk], acc10, 0, 0, 0);
            acc11 = __builtin_amdgcn_mfma_f32_16x16x32_bf16(a1, B1[1][kk], acc11, 0, 0, 0);
        }
#pragma unroll
        for (int q = 0; q < 4; ++q) {
            red1[wid][0][q][lane] = acc00[q];
            red1[wid][1][q][lane] = acc01[q];
            red1[wid][2][q][lane] = acc10[q];
            red1[wid][3][q][lane] = acc11[q];
        }
        __syncthreads();

        // ---- K-reduction across 4 waves + leaky h update + tanh + publish t ----
        float4 p0 = *(const float4*)&red1[0][st1][rg1][ln1];
        float4 p1 = *(const float4*)&red1[1][st1][rg1][ln1];
        float4 p2 = *(const float4*)&red1[2][st1][rg1][ln1];
        float4 p3 = *(const float4*)&red1[3][st1][rg1][ln1];
        float sx = p0.x + p1.x + p2.x + p3.x;
        float sy = p0.y + p1.y + p2.y + p3.y;
        float sz = p0.z + p1.z + p2.z + p3.z;
        float sw = p0.w + p1.w + p2.w + p3.w;
        hreg.x = 0.9f * hreg.x + 0.1f * (sx + br4.x);
        hreg.y = 0.9f * hreg.y + 0.1f * (sy + br4.y);
        hreg.z = 0.9f * hreg.z + 0.1f * (sz + br4.z);
        hreg.w = 0.9f * hreg.w + 0.1f * (sw + br4.w);
        ushort4 pk;
        pk.x = f2bf(fast_tanh(hreg.x));
        pk.y = f2bf(fast_tanh(hreg.y));
        pk.z = f2bf(fast_tanh(hreg.z));
        pk.w = f2bf(fast_tanh(hreg.w));
        *(ushort4*)(tn + t_off) = pk;

        arrive(i + 1);

        // ---- off-critical-path: err_{i-1} from t_i (triple buffer makes this safe) ----
        if (i >= 1) gemm2(tb, i - 1);

        wait(i + 1);
    }

    // ---- epilogue: err_{511} from t_512 ----
    gemm2(tbase + (size_t)(SEQ % 3) * (BATCH * SD), SEQ - 1);
}

extern "C" void kernel_launch(void* const* d_in, const int* in_sizes, int n_in,
                              void* d_out, int out_size, void* d_ws, size_t ws_size,
                              hipStream_t stream)
{
    const float* x      = (const float*)d_in[0];
    const float* h_init = (const float*)d_in[1];
    const float* w_r    = (const float*)d_in[2];
    const float* b_r    = (const float*)d_in[3];
    const float* w_o    = (const float*)d_in[4];
    const float* b_o    = (const float*)d_in[5];
    float* out = (float*)d_out;

    // ws layout: [0,2048) counters, [2048,4096) flags, [4096, 4096+3*512K) t triple buffer
    hipMemsetAsync(d_ws, 0, 4096, stream);
    rnn_persistent<<<dim3(256), dim3(256), 0, stream>>>(
        x, h_init, w_r, b_r, w_o, b_o, out, (unsigned char*)d_ws);
}

// Round 2
// 1967.030 us; speedup vs baseline: 2.8885x; 2.8885x over previous
//
#include <hip/hip_runtime.h>
#include <cstdint>
#include <cstddef>

#define SEQ 512
#define BATCH 256
#define SD 1024
#define OD 256
#define NG 16          // groups (batch tiles)
#define GB 16          // batches per group
#define NW 16          // workgroups per group

// 8 bf16 values packed as shorts (4 VGPRs) -- guide-verified MFMA frag type
typedef short  bf8   __attribute__((ext_vector_type(8)));
typedef float  f32x4 __attribute__((ext_vector_type(4)));

union BF16x8 { unsigned long long q[2]; bf8 v; };

__device__ __forceinline__ unsigned short f2bf(float f) {
    unsigned u = __float_as_uint(f);
    u += 0x7FFFu + ((u >> 16) & 1u);      // round-to-nearest-even
    return (unsigned short)(u >> 16);
}

__device__ __forceinline__ float fast_tanh(float v) {
    float e = __expf(2.0f * v);
    return 1.0f - 2.0f / (e + 1.0f);
}

// agent-scope (sc1) atomic access to the shared t buffer: bypasses L1/L2,
// always coherent at the device coherence point -> no wbl2/inv fences needed.
__device__ __forceinline__ bf8 t_load16(const unsigned short* p) {
    BF16x8 u;
    unsigned long long* q = (unsigned long long*)p;
    u.q[0] = __hip_atomic_load(q,     __ATOMIC_RELAXED, __HIP_MEMORY_SCOPE_AGENT);
    u.q[1] = __hip_atomic_load(q + 1, __ATOMIC_RELAXED, __HIP_MEMORY_SCOPE_AGENT);
    return u.v;
}
__device__ __forceinline__ void t_store8(unsigned short* p, float a, float b, float c, float d) {
    unsigned long long v = (unsigned long long)f2bf(a)
                         | ((unsigned long long)f2bf(b) << 16)
                         | ((unsigned long long)f2bf(c) << 32)
                         | ((unsigned long long)f2bf(d) << 48);
    __hip_atomic_store((unsigned long long*)p, v, __ATOMIC_RELAXED, __HIP_MEMORY_SCOPE_AGENT);
}

// Persistent kernel: 256 wgs = 16 groups (group = blockIdx&15 -> one XCD each,
// 2 groups/XCD) x 16 wgs. Group handles 16 batches; wg owns 64 state-cols of
// w_r (128 VGPRs of bf16 frags) and 16 out-cols of w_o (full MFMA N tile).
// Per step: load A frags (sc1) -> recurrent MFMA -> cross-wave LDS reduce ->
// h update (regs) -> tanh -> sc1 publish -> flag barrier (no fences) ->
// output GEMM for prev step reusing A frags (off critical path) -> wait.
__global__ void __launch_bounds__(256, 1)
rnn_persistent(const float* __restrict__ x,
               const float* __restrict__ h_init,
               const float* __restrict__ w_r,
               const float* __restrict__ b_r,
               const float* __restrict__ w_o,
               const float* __restrict__ b_o,
               float* __restrict__ out,
               unsigned char* __restrict__ ws)
{
    const int wg   = blockIdx.x;
    const int g    = wg & 15;      // group; members share blockIdx mod 8 -> same XCD
    const int wi   = wg >> 4;      // 0..15 within group
    const int tid  = threadIdx.x;
    const int lane = tid & 63;
    const int wid  = tid >> 6;     // wave 0..3
    const int l15  = lane & 15;
    const int lq   = lane >> 4;    // k-quad 0..3

    unsigned* cnt  = (unsigned*)(ws + (size_t)g * 128);
    unsigned* flag = (unsigned*)(ws + 2048 + (size_t)g * 128);
    unsigned short* tbase = (unsigned short*)(ws + 4096);  // 3 x [256][1024] bf16

    const int batch0 = g * GB;     // group's batch rows
    const int s0 = wi * 64;        // wg's state cols
    const int o0 = wi * 16;        // wg's output cols
    const int k0 = wid * 256;      // wave's K slice

    __shared__ float red1[4][4][4][68];  // [wave][coltile][reg][lane] (+4 pad: bank spread)
    __shared__ float red2[4][4][68];     // [wave][reg][lane]

    // ---- preload w_r slice as B fragments in registers (128 VGPRs) ----
    bf8 B1[4][8];
#pragma unroll
    for (int ct = 0; ct < 4; ++ct) {
#pragma unroll
        for (int kk = 0; kk < 8; ++kk) {
            const float* p = w_r + (size_t)(s0 + ct * 16 + l15) * SD + (k0 + kk * 32 + lq * 8);
            bf8 f;
#pragma unroll
            for (int j = 0; j < 8; ++j) f[j] = (short)f2bf(p[j]);
            B1[ct][kk] = f;
        }
    }
    // ---- w_o slice: 16 rows -> full N=16 tile, no padding ----
    bf8 B2[8];
#pragma unroll
    for (int kk = 0; kk < 8; ++kk) {
        const float* p = w_o + (size_t)(o0 + l15) * SD + (k0 + kk * 32 + lq * 8);
        bf8 f;
#pragma unroll
        for (int j = 0; j < 8; ++j) f[j] = (short)f2bf(p[j]);
        B2[kk] = f;
    }

    // ---- per-thread h ownership: 4 consecutive states of one batch row ----
    const int hr = tid >> 4;            // batch-local row 0..15
    const int hc = (tid & 15) * 4;      // state-local col base 0..60
    float4 br4  = *(const float4*)(b_r + s0 + hc);
    float4 hreg = *(const float4*)(h_init + (size_t)(batch0 + hr) * SD + s0 + hc);

    const int ct1 = hc >> 4;
    const int rg1 = hr & 3;
    const int ln1 = (hr >> 2) * 16 + (hc & 15);

    const int er  = tid >> 4;           // err element (row, col): one per thread
    const int ec  = tid & 15;
    const int rg2 = er & 3;
    const int ln2 = (er >> 2) * 16 + ec;
    const float bo = b_o[o0 + ec];

    const size_t t_off = (size_t)(batch0 + hr) * SD + s0 + hc;

    auto arrive = [&](unsigned phase) {
        __syncthreads();  // drains vmcnt: all sc1 t-stores visible at coherence point
        if (tid == 0) {
            unsigned old = __hip_atomic_fetch_add(cnt, 1u, __ATOMIC_RELAXED, __HIP_MEMORY_SCOPE_AGENT);
            if (old == phase * (unsigned)NW + (NW - 1))
                __hip_atomic_store(flag, phase + 1u, __ATOMIC_RELAXED, __HIP_MEMORY_SCOPE_AGENT);
        }
    };
    auto wait = [&](unsigned phase) {
        if (tid == 0) {
            while (__hip_atomic_load(flag, __ATOMIC_RELAXED, __HIP_MEMORY_SCOPE_AGENT) < phase + 1u)
                __builtin_amdgcn_s_sleep(1);
        }
        __syncthreads();
    };

    bf8 A[8];  // A fragments of current t tile (reused by gemm1 AND gemm2)

    auto gemm2 = [&](int tstep) {
        size_t oidx = (size_t)tstep * (BATCH * OD) + (size_t)(batch0 + er) * OD + o0 + ec;
        float xv = x[oidx];                       // issue early, overlaps MFMA
        f32x4 c = {0.f, 0.f, 0.f, 0.f};
#pragma unroll
        for (int kk = 0; kk < 8; ++kk)
            c = __builtin_amdgcn_mfma_f32_16x16x32_bf16(A[kk], B2[kk], c, 0, 0, 0);
#pragma unroll
        for (int q = 0; q < 4; ++q) red2[wid][q][lane] = c[q];
        __syncthreads();
        float sum = red2[0][rg2][ln2] + red2[1][rg2][ln2]
                  + red2[2][rg2][ln2] + red2[3][rg2][ln2];
        out[oidx] = sum + bo - xv;
    };

    // ---- t0 = tanh(h_init) into buffer 0 ----
    t_store8(tbase + t_off, fast_tanh(hreg.x), fast_tanh(hreg.y),
                            fast_tanh(hreg.z), fast_tanh(hreg.w));
    arrive(0);
    wait(0);

    for (int i = 0; i < SEQ; ++i) {
        const unsigned short* tb = tbase + (size_t)(i % 3) * (BATCH * SD);
        unsigned short* tn = tbase + (size_t)((i + 1) % 3) * (BATCH * SD);

        // ---- A fragments: 16 rows x wave's K slice, sc1 loads (coherence pt) ----
        const unsigned short* ap = tb + (size_t)(batch0 + l15) * SD + k0 + lq * 8;
#pragma unroll
        for (int kk = 0; kk < 8; ++kk) A[kk] = t_load16(ap + kk * 32);

        // ---- recurrent GEMM: C[16x64] per wave over its K slice ----
        f32x4 acc0 = {0.f,0.f,0.f,0.f}, acc1 = {0.f,0.f,0.f,0.f};
        f32x4 acc2 = {0.f,0.f,0.f,0.f}, acc3 = {0.f,0.f,0.f,0.f};
#pragma unroll
        for (int kk = 0; kk < 8; ++kk) {
            acc0 = __builtin_amdgcn_mfma_f32_16x16x32_bf16(A[kk], B1[0][kk], acc0, 0, 0, 0);
            acc1 = __builtin_amdgcn_mfma_f32_16x16x32_bf16(A[kk], B1[1][kk], acc1, 0, 0, 0);
            acc2 = __builtin_amdgcn_mfma_f32_16x16x32_bf16(A[kk], B1[2][kk], acc2, 0, 0, 0);
            acc3 = __builtin_amdgcn_mfma_f32_16x16x32_bf16(A[kk], B1[3][kk], acc3, 0, 0, 0);
        }
#pragma unroll
        for (int q = 0; q < 4; ++q) {
            red1[wid][0][q][lane] = acc0[q];
            red1[wid][1][q][lane] = acc1[q];
            red1[wid][2][q][lane] = acc2[q];
            red1[wid][3][q][lane] = acc3[q];
        }
        __syncthreads();

        // ---- K-reduction across 4 waves + leaky h update + tanh + publish ----
        float4 p0 = *(const float4*)&red1[0][ct1][rg1][ln1];
        float4 p1 = *(const float4*)&red1[1][ct1][rg1][ln1];
        float4 p2 = *(const float4*)&red1[2][ct1][rg1][ln1];
        float4 p3 = *(const float4*)&red1[3][ct1][rg1][ln1];
        hreg.x = 0.9f * hreg.x + 0.1f * (p0.x + p1.x + p2.x + p3.x + br4.x);
        hreg.y = 0.9f * hreg.y + 0.1f * (p0.y + p1.y + p2.y + p3.y + br4.y);
        hreg.z = 0.9f * hreg.z + 0.1f * (p0.z + p1.z + p2.z + p3.z + br4.z);
        hreg.w = 0.9f * hreg.w + 0.1f * (p0.w + p1.w + p2.w + p3.w + br4.w);
        t_store8(tn + t_off, fast_tanh(hreg.x), fast_tanh(hreg.y),
                             fast_tanh(hreg.z), fast_tanh(hreg.w));

        arrive(i + 1);

        // ---- off-critical-path: err_{i-1} reuses this step's A frags ----
        if (i >= 1) gemm2(i - 1);

        wait(i + 1);
    }

    // ---- epilogue: err_{511} from t_512 (published; last wait ordered it) ----
    {
        const unsigned short* tb = tbase + (size_t)(SEQ % 3) * (BATCH * SD);
        const unsigned short* ap = tb + (size_t)(batch0 + l15) * SD + k0 + lq * 8;
#pragma unroll
        for (int kk = 0; kk < 8; ++kk) A[kk] = t_load16(ap + kk * 32);
        gemm2(SEQ - 1);
    }
}

extern "C" void kernel_launch(void* const* d_in, const int* in_sizes, int n_in,
                              void* d_out, int out_size, void* d_ws, size_t ws_size,
                              hipStream_t stream)
{
    const float* x      = (const float*)d_in[0];
    const float* h_init = (const float*)d_in[1];
    const float* w_r    = (const float*)d_in[2];
    const float* b_r    = (const float*)d_in[3];
    const float* w_o    = (const float*)d_in[4];
    const float* b_o    = (const float*)d_in[5];
    float* out = (float*)d_out;

    // ws layout: [0,2048) counters, [2048,4096) flags, [4096, +3*512K) t triple buffer
    hipMemsetAsync(d_ws, 0, 4096, stream);
    rnn_persistent<<<dim3(256), dim3(256), 0, stream>>>(
        x, h_init, w_r, b_r, w_o, b_o, out, (unsigned char*)d_ws);
}